// Round 13
// baseline (284.779 us; speedup 1.0000x reference)
//
#include <hip/hip_runtime.h>
#include <hip/hip_bf16.h>

#define D 128
#define KTERMS 16
#define ECAP 768

typedef __attribute__((ext_vector_type(8))) short bf16x8;
typedef __attribute__((ext_vector_type(4))) float f32x4;

__device__ inline short rne_bf16(float f) {
    union { float f; unsigned u; } v; v.f = f;
    unsigned r = (v.u + 0x7fffu + ((v.u >> 16) & 1u)) >> 16;
    return (short)r;
}
__device__ inline float bf16_to_f(unsigned s) {
    union { unsigned u; float f; } v; v.u = s << 16;
    return v.f;
}
__device__ inline unsigned pk2(float a, float b) {
    return (unsigned)(unsigned short)rne_bf16(a) | ((unsigned)(unsigned short)rne_bf16(b) << 16);
}
__device__ inline void addv(float* acc, uint4 v) {
    acc[0] += bf16_to_f(v.x & 0xffffu);
    acc[1] += bf16_to_f(v.x >> 16);
    acc[2] += bf16_to_f(v.y & 0xffffu);
    acc[3] += bf16_to_f(v.y >> 16);
    acc[4] += bf16_to_f(v.z & 0xffffu);
    acc[5] += bf16_to_f(v.z >> 16);
    acc[6] += bf16_to_f(v.w & 0xffffu);
    acc[7] += bf16_to_f(v.w >> 16);
}

// ---------- prep: cvt x->bf16 [0,1024) | weights [1024,1280) | zero ints [1280,1312) | zero M [1312] ----------
__global__ __launch_bounds__(256) void prep_kernel(const float* __restrict__ x,
                                                   short* __restrict__ xb,
                                                   const float* __restrict__ W1l,
                                                   const float* __restrict__ W1r,
                                                   const float* __restrict__ W2l,
                                                   const float* __restrict__ W2r,
                                                   short* __restrict__ Bc1,
                                                   short* __restrict__ Bc2,
                                                   int* __restrict__ zero_ints,   // degi+cursor, 2N ints
                                                   float* __restrict__ zero_f) {  // M+mden
    int b = blockIdx.x;
    int tid = threadIdx.x;
    if (b < 1024) {
        int base = (b * 256 + tid) * 8;
        const float4 a = *reinterpret_cast<const float4*>(&x[base]);
        const float4 c = *reinterpret_cast<const float4*>(&x[base + 4]);
        uint4 o;
        o.x = pk2(a.x, a.y);
        o.y = pk2(a.z, a.w);
        o.z = pk2(c.x, c.y);
        o.w = pk2(c.z, c.w);
        *reinterpret_cast<uint4*>(&xb[base]) = o;
    } else if (b < 1280) {
        int idx = (b - 1024) * 256 + tid;   // 65536 total
        int layer = idx >> 15;
        int rem = idx & 32767;
        int c = rem >> 8, k = rem & 255;
        const float* Wl = layer ? W2l : W1l;
        const float* Wr = layer ? W2r : W1r;
        float v = (k < 128) ? Wl[c * 128 + k] : Wr[c * 128 + (k - 128)];
        short* Bc = layer ? Bc2 : Bc1;
        Bc[c * 256 + k] = rne_bf16(v);
    } else if (b < 1312) {
        int idx = (b - 1280) * 256 + tid;   // 8192 int4 = 2N ints
        reinterpret_cast<int4*>(zero_ints)[idx] = make_int4(0, 0, 0, 0);
    } else {
        for (int e = tid; e < KTERMS * D + KTERMS; e += 256) zero_f[e] = 0.0f;
    }
}

// ---------- int degree histogram ----------
__global__ __launch_bounds__(256) void degi_kernel(const int* __restrict__ dst,
                                                   int* __restrict__ degi, int E) {
    int e = blockIdx.x * 256 + threadIdx.x;
    if (e < E) atomicAdd(&degi[dst[e]], 1);
}

// ---------- exclusive prefix scan of degi -> rowptr, plus invdeg ----------
__global__ __launch_bounds__(1024) void scan_kernel(const int* __restrict__ degi,
                                                    int* __restrict__ rowptr,
                                                    float* __restrict__ invdeg, int N) {
    __shared__ int part[1024];
    int tid = threadIdx.x;
    int base = tid * 16;
    int loc[16];
    int s = 0;
#pragma unroll
    for (int i = 0; i < 16; i++) {
        int d = degi[base + i];
        loc[i] = s; s += d;
        invdeg[base + i] = 1.0f / fmaxf((float)d, 1.0f);
    }
    part[tid] = s;
    __syncthreads();
    for (int off = 1; off < 1024; off <<= 1) {
        int t = (tid >= off) ? part[tid - off] : 0;
        __syncthreads();
        if (tid >= off) part[tid] += t;
        __syncthreads();
    }
    int prefix = part[tid] - s;  // exclusive
#pragma unroll
    for (int i = 0; i < 16; i++) rowptr[base + i] = prefix + loc[i];
    if (tid == 1023) rowptr[N] = prefix + s;
}

// ---------- CSR fill ----------
__global__ __launch_bounds__(256) void fill_kernel(const int* __restrict__ src,
                                                   const int* __restrict__ dst,
                                                   const int* __restrict__ rowptr,
                                                   int* __restrict__ cursor,
                                                   int* __restrict__ csr_src, int E) {
    int e = blockIdx.x * 256 + threadIdx.x;
    if (e < E) {
        int d = dst[e];
        int pos = atomicAdd(&cursor[d], 1);
        csr_src[rowptr[d] + pos] = src[e];
    }
}

// ---------- fused gather + MFMA SAGE (+ score + moments epilogue when SCORE) ----------
// Block: 256 thr = 4 waves; 16 rows x 128 cols. Grid N/16 = 1024.
template <int RELU, int SCORE>
__global__ __launch_bounds__(256) void sage_fused_kernel(const short* __restrict__ Asrc,
                                                         const short* __restrict__ Bc,
                                                         const float* __restrict__ bias,
                                                         const int* __restrict__ rowptr,
                                                         const int* __restrict__ csr_src,
                                                         const float* __restrict__ invdeg,
                                                         const float* __restrict__ aux,
                                                         short* __restrict__ outb,
                                                         float* __restrict__ outf,
                                                         float* __restrict__ sbuf,
                                                         float* __restrict__ M,
                                                         float* __restrict__ mden) {
    __shared__ short aggl[16 * 128];      // 4 KB swizzled
    __shared__ int eidx[ECAP];            // 3 KB staged CSR indices
    __shared__ float sdot[16][4];
    __shared__ float snrm[16][4];
    __shared__ float sws[16];
    __shared__ float wws[16];
    __shared__ float an_s;

    int tid = threadIdx.x;
    int lane = tid & 63;
    int wid = tid >> 6;
    int row0 = blockIdx.x * 16;
    int sub = lane >> 4, sl = lane & 15;

    // stage this block's CSR index window into LDS (coalesced)
    int eb = rowptr[row0];
    int ecnt = rowptr[row0 + 16] - eb;
    for (int e = tid; e < ecnt && e < ECAP; e += 256) eidx[e] = csr_src[eb + e];

    if (SCORE && wid == 0) {
        float2 av = *reinterpret_cast<const float2*>(&aux[lane * 2]);
        float na = av.x * av.x + av.y * av.y;
        for (int m = 1; m < 64; m <<= 1) na += __shfl_xor(na, m);
        if (lane == 0) an_s = fmaxf(sqrtf(na), 1e-8f);
    }
    __syncthreads();

    // ---- gather phase: 1 node per 16-lane subgroup, LDS indices, unroll-4 ----
    int r = wid * 4 + sub;
    int node = row0 + r;
    int beg = rowptr[node], end = rowptr[node + 1];
    float inv = invdeg[node];
    float acc8[8] = {0.0f, 0.0f, 0.0f, 0.0f, 0.0f, 0.0f, 0.0f, 0.0f};
    int j = beg;
    for (; j + 3 < end; j += 4) {
        int jj = j - eb;
        int s0, s1, s2, s3;
        if (jj + 3 < ECAP) {
            s0 = eidx[jj]; s1 = eidx[jj + 1]; s2 = eidx[jj + 2]; s3 = eidx[jj + 3];
        } else {
            s0 = csr_src[j]; s1 = csr_src[j + 1]; s2 = csr_src[j + 2]; s3 = csr_src[j + 3];
        }
        uint4 v0 = *reinterpret_cast<const uint4*>(&Asrc[(size_t)s0 * D + sl * 8]);
        uint4 v1 = *reinterpret_cast<const uint4*>(&Asrc[(size_t)s1 * D + sl * 8]);
        uint4 v2 = *reinterpret_cast<const uint4*>(&Asrc[(size_t)s2 * D + sl * 8]);
        uint4 v3 = *reinterpret_cast<const uint4*>(&Asrc[(size_t)s3 * D + sl * 8]);
        addv(acc8, v0); addv(acc8, v1); addv(acc8, v2); addv(acc8, v3);
    }
    for (; j < end; j++) {
        int jj = j - eb;
        int s = (jj < ECAP) ? eidx[jj] : csr_src[j];
        uint4 v = *reinterpret_cast<const uint4*>(&Asrc[(size_t)s * D + sl * 8]);
        addv(acc8, v);
    }
    uint4 o;
    o.x = pk2(acc8[0] * inv, acc8[1] * inv);
    o.y = pk2(acc8[2] * inv, acc8[3] * inv);
    o.z = pk2(acc8[4] * inv, acc8[5] * inv);
    o.w = pk2(acc8[6] * inv, acc8[7] * inv);
    int wbyte = (r * 256 + sl * 16) ^ ((r & 7) << 4);
    *reinterpret_cast<uint4*>(reinterpret_cast<char*>(aggl) + wbyte) = o;
    __syncthreads();

    // ---- MFMA phase: wave owns 32 cols x 16 rows ----
    int colbase = wid * 32;
    int rl = lane & 15;
    int kg = lane >> 4;          // 0..3
    int koff = kg * 8;
    int arow_g = row0 + rl;

    f32x4 acc[2];
    acc[0] = (f32x4){0.0f, 0.0f, 0.0f, 0.0f};
    acc[1] = (f32x4){0.0f, 0.0f, 0.0f, 0.0f};

#pragma unroll
    for (int kc = 0; kc < 8; kc++) {
        bf16x8 a;
        if (kc < 4) {
            int rbyte = (rl * 256 + kc * 64 + kg * 16) ^ ((rl & 7) << 4);
            a = *reinterpret_cast<const bf16x8*>(reinterpret_cast<const char*>(aggl) + rbyte);
        } else {
            int k = (kc - 4) * 32 + koff;
            a = *reinterpret_cast<const bf16x8*>(&Asrc[(size_t)arow_g * D + k]);
        }
#pragma unroll
        for (int t = 0; t < 2; t++) {
            int col = colbase + t * 16 + rl;
            bf16x8 b = *reinterpret_cast<const bf16x8*>(&Bc[(size_t)col * 256 + kc * 32 + koff]);
            acc[t] = __builtin_amdgcn_mfma_f32_16x16x32_bf16(a, b, acc[t], 0, 0, 0);
        }
    }

    // ---- epilogue: bias + relu + store; keep v for score/moments ----
    int rbase = kg * 4;
    float vkeep0[4], vkeep1[4];
    float dotp[4] = {0.0f, 0.0f, 0.0f, 0.0f};
    float nrmp[4] = {0.0f, 0.0f, 0.0f, 0.0f};
    {
        int col0 = colbase + rl;
        int col1 = colbase + 16 + rl;
        float bv0 = bias[col0], bv1 = bias[col1];
        float av0 = SCORE ? aux[col0] : 0.0f;
        float av1 = SCORE ? aux[col1] : 0.0f;
#pragma unroll
        for (int rr = 0; rr < 4; rr++) {
            float v0 = acc[0][rr] + bv0;
            float v1 = acc[1][rr] + bv1;
            if (RELU) { v0 = fmaxf(v0, 0.0f); v1 = fmaxf(v1, 0.0f); }
            int grow = row0 + rbase + rr;
            if (outf) {
                outf[(size_t)grow * D + col0] = v0;
                outf[(size_t)grow * D + col1] = v1;
            } else {
                outb[(size_t)grow * D + col0] = rne_bf16(v0);
                outb[(size_t)grow * D + col1] = rne_bf16(v1);
            }
            vkeep0[rr] = v0; vkeep1[rr] = v1;
            dotp[rr] += v0 * av0 + v1 * av1;
            nrmp[rr] += v0 * v0 + v1 * v1;
        }
    }

    if (SCORE) {
        // score reduce across 16 col-lanes
#pragma unroll
        for (int m = 1; m < 16; m <<= 1) {
#pragma unroll
            for (int rr = 0; rr < 4; rr++) {
                dotp[rr] += __shfl_xor(dotp[rr], m);
                nrmp[rr] += __shfl_xor(nrmp[rr], m);
            }
        }
        if (rl == 0) {
#pragma unroll
            for (int rr = 0; rr < 4; rr++) {
                sdot[rbase + rr][wid] = dotp[rr];
                snrm[rbase + rr][wid] = nrmp[rr];
            }
        }
        __syncthreads();
        if (tid < 16) {
            float dot = sdot[tid][0] + sdot[tid][1] + sdot[tid][2] + sdot[tid][3];
            float nh  = snrm[tid][0] + snrm[tid][1] + snrm[tid][2] + snrm[tid][3];
            float hn = fmaxf(sqrtf(nh), 1e-8f);
            float sc = dot / (hn * an_s);
            float w = expf(-sc * sc);
            sbuf[row0 + tid] = sc;
            sws[tid] = sc;
            wws[tid] = w;
            // mden: reduce w*s^k over the 16 rows (lanes 0-15 of wave 0)
            float coef = w;
#pragma unroll
            for (int k = 0; k < KTERMS; k++) {
                float v = coef;
#pragma unroll
                for (int m = 1; m < 16; m <<= 1) v += __shfl_xor(v, m);
                if (tid == 0) atomicAdd(&mden[k], v);
                coef *= sc;
            }
        }
        __syncthreads();

        // moments: c[k] = sum_rows w*s^k*v for this thread's 2 cols
        float c0[KTERMS], c1[KTERMS];
#pragma unroll
        for (int k = 0; k < KTERMS; k++) { c0[k] = 0.0f; c1[k] = 0.0f; }
#pragma unroll
        for (int rr = 0; rr < 4; rr++) {
            int row = rbase + rr;
            float srow = sws[row];
            float coef = wws[row];
            float v0 = vkeep0[rr], v1 = vkeep1[rr];
#pragma unroll
            for (int k = 0; k < KTERMS; k++) {
                c0[k] += coef * v0;
                c1[k] += coef * v1;
                coef *= srow;
            }
        }
        // reduce over the 4 row-groups (lanes stride 16)
#pragma unroll
        for (int m = 16; m < 64; m <<= 1) {
#pragma unroll
            for (int k = 0; k < KTERMS; k++) {
                c0[k] += __shfl_xor(c0[k], m);
                c1[k] += __shfl_xor(c1[k], m);
            }
        }
        if (kg == 0) {
            int col0 = colbase + rl;
            int col1 = colbase + 16 + rl;
#pragma unroll
            for (int k = 0; k < KTERMS; k++) {
                atomicAdd(&M[k * D + col0], c0[k]);
                atomicAdd(&M[k * D + col1], c1[k]);
            }
        }
    }
}

// ---------- fused z + classifier: out[n][c] = [h,z]@Wc^T + bc ----------
__global__ __launch_bounds__(128) void zcls_kernel(const float* __restrict__ M,
                                                   const float* __restrict__ mden,
                                                   const float* __restrict__ sbuf,
                                                   const float* __restrict__ h,
                                                   const float* __restrict__ Wc,
                                                   const float* __restrict__ bc,
                                                   float* __restrict__ out, int N) {
    const float A[KTERMS] = {1.0f, 2.0f, 2.0f, 1.3333334f, 0.6666667f, 0.26666668f,
                             0.08888889f, 0.025396826f, 0.0063492064f, 0.0014109347f,
                             2.8218695e-4f, 5.1306718e-5f, 8.5511196e-6f, 1.3155569e-6f,
                             1.8793670e-7f, 2.5058226e-8f};
    __shared__ float Ml[KTERMS * D];
    __shared__ float ml[KTERMS];
    __shared__ float wls[10 * 256];
    __shared__ float red[10][2];
    int tid = threadIdx.x;
    int lane = tid & 63, w = tid >> 6;
#pragma unroll
    for (int k = 0; k < KTERMS; k++) Ml[k * D + tid] = M[k * D + tid];
    if (tid < KTERMS) ml[tid] = mden[tid];
    for (int e = tid; e < 10 * 256; e += 128) wls[e] = Wc[e];
    __syncthreads();

    int n0 = blockIdx.x * 16;
    for (int n = n0; n < n0 + 16; n++) {
        float si = sbuf[n];
        float num = 0.0f, den = 0.0f, p = 1.0f;
#pragma unroll
        for (int k = 0; k < KTERMS; k++) {
            float ck = A[k] * p;
            num += ck * Ml[k * D + tid];
            den += ck * ml[k];
            p *= si;
        }
        float zc = num / den;
        float hc = h[(size_t)n * D + tid];

        float part[10];
#pragma unroll
        for (int c = 0; c < 10; c++)
            part[c] = hc * wls[c * 256 + tid] + zc * wls[c * 256 + 128 + tid];
#pragma unroll
        for (int m = 1; m < 64; m <<= 1) {
#pragma unroll
            for (int c = 0; c < 10; c++) part[c] += __shfl_xor(part[c], m);
        }
        if (lane == 0) {
#pragma unroll
            for (int c = 0; c < 10; c++) red[c][w] = part[c];
        }
        __syncthreads();
        if (tid < 10) out[(size_t)n * 10 + tid] = red[tid][0] + red[tid][1] + bc[tid];
        __syncthreads();
    }
}

extern "C" void kernel_launch(void* const* d_in, const int* in_sizes, int n_in,
                              void* d_out, int out_size, void* d_ws, size_t ws_size,
                              hipStream_t stream) {
    const float* x   = (const float*)d_in[0];
    const int*   ei  = (const int*)d_in[1];
    const float* W1l = (const float*)d_in[2];
    const float* b1l = (const float*)d_in[3];
    const float* W1r = (const float*)d_in[4];
    const float* W2l = (const float*)d_in[5];
    const float* b2l = (const float*)d_in[6];
    const float* W2r = (const float*)d_in[7];
    const float* aux = (const float*)d_in[8];
    const float* Wc  = (const float*)d_in[9];
    const float* bc  = (const float*)d_in[10];
    float* out = (float*)d_out;

    const int N = in_sizes[0] / D;
    const int E = in_sizes[1] / 2;
    const int* srcArr = ei;
    const int* dstArr = ei + E;
    const size_t ND = (size_t)N * D;

    // ---- workspace carve-up ----
    int* ip = (int*)d_ws;
    int* degi    = ip; ip += N;
    int* cursor  = ip; ip += N;
    int* rowptr  = ip; ip += N + 1;
    int* csr_src = ip; ip += E;
    uintptr_t up = ((uintptr_t)ip + 15) & ~(uintptr_t)15;
    short* sp = (short*)up;
    short* xb   = sp; sp += ND;
    short* h1b  = sp; sp += ND;
    short* Bc1  = sp; sp += 128 * 256;
    short* Bc2  = sp; sp += 128 * 256;
    up = ((uintptr_t)sp + 15) & ~(uintptr_t)15;
    float* p = (float*)up;
    float* invdeg = p; p += N;
    float* sbuf   = p; p += N;
    float* M      = p; p += KTERMS * D;
    float* mden   = p; p += KTERMS;
    float* h2     = p; p += ND;

    // prep: x->bf16, weight concat, zero degi/cursor and M/mden
    prep_kernel<<<1313, 256, 0, stream>>>(x, xb, W1l, W1r, W2l, W2r, Bc1, Bc2, degi, M);

    // build CSR (sorted by dst)
    degi_kernel<<<(E + 255) / 256, 256, 0, stream>>>(dstArr, degi, E);
    scan_kernel<<<1, 1024, 0, stream>>>(degi, rowptr, invdeg, N);
    fill_kernel<<<(E + 255) / 256, 256, 0, stream>>>(srcArr, dstArr, rowptr, cursor, csr_src, E);

    // layer 1: h1b = relu([gather(xb)|xb] @ Bc1^T + b1l)
    sage_fused_kernel<1, 0><<<N / 16, 256, 0, stream>>>(xb, Bc1, b1l, rowptr, csr_src, invdeg,
                                                        aux, h1b, nullptr, nullptr, nullptr, nullptr);
    // layer 2: h2 = [gather(h1b)|h1b] @ Bc2^T + b2l, + score + moments epilogue
    sage_fused_kernel<0, 1><<<N / 16, 256, 0, stream>>>(h1b, Bc2, b2l, rowptr, csr_src, invdeg,
                                                        aux, nullptr, h2, sbuf, M, mden);

    // fused z + classifier
    zcls_kernel<<<N / 16, 128, 0, stream>>>(M, mden, sbuf, h2, Wc, bc, out, N);
}

// Round 14
// 155.104 us; speedup vs baseline: 1.8361x; 1.8361x over previous
//
#include <hip/hip_runtime.h>
#include <hip/hip_bf16.h>

#define D 128
#define KTERMS 16
#define ECAP 768

typedef __attribute__((ext_vector_type(8))) short bf16x8;
typedef __attribute__((ext_vector_type(4))) float f32x4;

__device__ inline short rne_bf16(float f) {
    union { float f; unsigned u; } v; v.f = f;
    unsigned r = (v.u + 0x7fffu + ((v.u >> 16) & 1u)) >> 16;
    return (short)r;
}
__device__ inline float bf16_to_f(unsigned s) {
    union { unsigned u; float f; } v; v.u = s << 16;
    return v.f;
}
__device__ inline unsigned pk2(float a, float b) {
    return (unsigned)(unsigned short)rne_bf16(a) | ((unsigned)(unsigned short)rne_bf16(b) << 16);
}
__device__ inline void addv(float* acc, uint4 v) {
    acc[0] += bf16_to_f(v.x & 0xffffu);
    acc[1] += bf16_to_f(v.x >> 16);
    acc[2] += bf16_to_f(v.y & 0xffffu);
    acc[3] += bf16_to_f(v.y >> 16);
    acc[4] += bf16_to_f(v.z & 0xffffu);
    acc[5] += bf16_to_f(v.z >> 16);
    acc[6] += bf16_to_f(v.w & 0xffffu);
    acc[7] += bf16_to_f(v.w >> 16);
}

// ---------- prep: cvt x->bf16 [0,1024) | weights [1024,1280) | zero ints [1280,1312) | zero M [1312] ----------
__global__ __launch_bounds__(256) void prep_kernel(const float* __restrict__ x,
                                                   short* __restrict__ xb,
                                                   const float* __restrict__ W1l,
                                                   const float* __restrict__ W1r,
                                                   const float* __restrict__ W2l,
                                                   const float* __restrict__ W2r,
                                                   short* __restrict__ Bc1,
                                                   short* __restrict__ Bc2,
                                                   int* __restrict__ zero_ints,   // degi+cursor, 2N ints
                                                   float* __restrict__ zero_f) {  // M+mden
    int b = blockIdx.x;
    int tid = threadIdx.x;
    if (b < 1024) {
        int base = (b * 256 + tid) * 8;
        const float4 a = *reinterpret_cast<const float4*>(&x[base]);
        const float4 c = *reinterpret_cast<const float4*>(&x[base + 4]);
        uint4 o;
        o.x = pk2(a.x, a.y);
        o.y = pk2(a.z, a.w);
        o.z = pk2(c.x, c.y);
        o.w = pk2(c.z, c.w);
        *reinterpret_cast<uint4*>(&xb[base]) = o;
    } else if (b < 1280) {
        int idx = (b - 1024) * 256 + tid;   // 65536 total
        int layer = idx >> 15;
        int rem = idx & 32767;
        int c = rem >> 8, k = rem & 255;
        const float* Wl = layer ? W2l : W1l;
        const float* Wr = layer ? W2r : W1r;
        float v = (k < 128) ? Wl[c * 128 + k] : Wr[c * 128 + (k - 128)];
        short* Bc = layer ? Bc2 : Bc1;
        Bc[c * 256 + k] = rne_bf16(v);
    } else if (b < 1312) {
        int idx = (b - 1280) * 256 + tid;   // 8192 int4 = 2N ints
        reinterpret_cast<int4*>(zero_ints)[idx] = make_int4(0, 0, 0, 0);
    } else {
        for (int e = tid; e < KTERMS * D + KTERMS; e += 256) zero_f[e] = 0.0f;
    }
}

// ---------- int degree histogram ----------
__global__ __launch_bounds__(256) void degi_kernel(const int* __restrict__ dst,
                                                   int* __restrict__ degi, int E) {
    int e = blockIdx.x * 256 + threadIdx.x;
    if (e < E) atomicAdd(&degi[dst[e]], 1);
}

// ---------- exclusive prefix scan of degi -> rowptr, plus invdeg ----------
__global__ __launch_bounds__(1024) void scan_kernel(const int* __restrict__ degi,
                                                    int* __restrict__ rowptr,
                                                    float* __restrict__ invdeg, int N) {
    __shared__ int part[1024];
    int tid = threadIdx.x;
    int base = tid * 16;
    int loc[16];
    int s = 0;
#pragma unroll
    for (int i = 0; i < 16; i++) {
        int d = degi[base + i];
        loc[i] = s; s += d;
        invdeg[base + i] = 1.0f / fmaxf((float)d, 1.0f);
    }
    part[tid] = s;
    __syncthreads();
    for (int off = 1; off < 1024; off <<= 1) {
        int t = (tid >= off) ? part[tid - off] : 0;
        __syncthreads();
        if (tid >= off) part[tid] += t;
        __syncthreads();
    }
    int prefix = part[tid] - s;  // exclusive
#pragma unroll
    for (int i = 0; i < 16; i++) rowptr[base + i] = prefix + loc[i];
    if (tid == 1023) rowptr[N] = prefix + s;
}

// ---------- CSR fill ----------
__global__ __launch_bounds__(256) void fill_kernel(const int* __restrict__ src,
                                                   const int* __restrict__ dst,
                                                   const int* __restrict__ rowptr,
                                                   int* __restrict__ cursor,
                                                   int* __restrict__ csr_src, int E) {
    int e = blockIdx.x * 256 + threadIdx.x;
    if (e < E) {
        int d = dst[e];
        int pos = atomicAdd(&cursor[d], 1);
        csr_src[rowptr[d] + pos] = src[e];
    }
}

// ---------- fused gather + MFMA SAGE (+ score epilogue when SCORE) ----------
// Block: 256 thr = 4 waves; 8 rows x 128 cols. Grid N/8 = 2048 (8 blocks/CU -> 100% wave cap).
// Gather: 2 x 16-lane subgroups per node (stride-2 edge split), shfl-combined.
// MFMA: 16-row tiles with rows 8-15 garbage; stores guarded (kg<2).
template <int RELU, int SCORE>
__global__ __launch_bounds__(256) void sage_fused_kernel(const short* __restrict__ Asrc,
                                                         const short* __restrict__ Bc,
                                                         const float* __restrict__ bias,
                                                         const int* __restrict__ rowptr,
                                                         const int* __restrict__ csr_src,
                                                         const float* __restrict__ invdeg,
                                                         const float* __restrict__ aux,
                                                         short* __restrict__ outb,
                                                         float* __restrict__ outf,
                                                         float* __restrict__ sbuf,
                                                         float* __restrict__ wbuf) {
    __shared__ short aggl[16 * 128];      // 4 KB swizzled (rows 8-15 unused)
    __shared__ int eidx[ECAP];            // 3 KB staged CSR indices
    __shared__ float sdot[8][4];
    __shared__ float snrm[8][4];
    __shared__ float an_s;

    int tid = threadIdx.x;
    int lane = tid & 63;
    int wid = tid >> 6;
    int row0 = blockIdx.x * 8;
    int sl = tid & 15;

    // stage this block's CSR index window into LDS (coalesced)
    int eb = rowptr[row0];
    int ecnt = rowptr[row0 + 8] - eb;
    for (int e = tid; e < ecnt && e < ECAP; e += 256) eidx[e] = csr_src[eb + e];

    if (SCORE && wid == 0) {
        float2 av = *reinterpret_cast<const float2*>(&aux[lane * 2]);
        float na = av.x * av.x + av.y * av.y;
        for (int m = 1; m < 64; m <<= 1) na += __shfl_xor(na, m);
        if (lane == 0) an_s = fmaxf(sqrtf(na), 1e-8f);
    }
    __syncthreads();

    // ---- gather phase: 2 subgroups per node, stride-2 halves, unroll-4 ----
    int sg = tid >> 4;            // 0..15
    int half = sg & 1;
    int r = sg >> 1;              // 0..7
    int node = row0 + r;
    int beg = rowptr[node], end = rowptr[node + 1];
    float inv = invdeg[node];
    float acc8[8] = {0.0f, 0.0f, 0.0f, 0.0f, 0.0f, 0.0f, 0.0f, 0.0f};
    int j = beg + half;
    for (; j + 6 < end; j += 8) {
        int jj = j - eb;
        int s0, s1, s2, s3;
        if (jj + 6 < ECAP) {
            s0 = eidx[jj]; s1 = eidx[jj + 2]; s2 = eidx[jj + 4]; s3 = eidx[jj + 6];
        } else {
            s0 = csr_src[j]; s1 = csr_src[j + 2]; s2 = csr_src[j + 4]; s3 = csr_src[j + 6];
        }
        uint4 v0 = *reinterpret_cast<const uint4*>(&Asrc[(size_t)s0 * D + sl * 8]);
        uint4 v1 = *reinterpret_cast<const uint4*>(&Asrc[(size_t)s1 * D + sl * 8]);
        uint4 v2 = *reinterpret_cast<const uint4*>(&Asrc[(size_t)s2 * D + sl * 8]);
        uint4 v3 = *reinterpret_cast<const uint4*>(&Asrc[(size_t)s3 * D + sl * 8]);
        addv(acc8, v0); addv(acc8, v1); addv(acc8, v2); addv(acc8, v3);
    }
    for (; j < end; j += 2) {
        int jj = j - eb;
        int s = (jj < ECAP) ? eidx[jj] : csr_src[j];
        uint4 v = *reinterpret_cast<const uint4*>(&Asrc[(size_t)s * D + sl * 8]);
        addv(acc8, v);
    }
    // combine the two halves (lanes sg and sg^1 swap via lane xor 16)
#pragma unroll
    for (int u = 0; u < 8; u++) acc8[u] += __shfl_xor(acc8[u], 16);
    if (half == 0) {
        uint4 o;
        o.x = pk2(acc8[0] * inv, acc8[1] * inv);
        o.y = pk2(acc8[2] * inv, acc8[3] * inv);
        o.z = pk2(acc8[4] * inv, acc8[5] * inv);
        o.w = pk2(acc8[6] * inv, acc8[7] * inv);
        int wbyte = (r * 256 + sl * 16) ^ ((r & 7) << 4);
        *reinterpret_cast<uint4*>(reinterpret_cast<char*>(aggl) + wbyte) = o;
    }
    __syncthreads();

    // ---- MFMA phase: wave owns 32 cols x 16 rows (8 valid) ----
    int colbase = wid * 32;
    int rl = lane & 15;
    int kg = lane >> 4;          // 0..3
    int koff = kg * 8;
    int arow_g = row0 + rl;      // rl 8-15 read garbage (in-workspace), discarded

    f32x4 acc[2];
    acc[0] = (f32x4){0.0f, 0.0f, 0.0f, 0.0f};
    acc[1] = (f32x4){0.0f, 0.0f, 0.0f, 0.0f};

#pragma unroll
    for (int kc = 0; kc < 8; kc++) {
        bf16x8 a;
        if (kc < 4) {
            int rbyte = (rl * 256 + kc * 64 + kg * 16) ^ ((rl & 7) << 4);
            a = *reinterpret_cast<const bf16x8*>(reinterpret_cast<const char*>(aggl) + rbyte);
        } else {
            int k = (kc - 4) * 32 + koff;
            a = *reinterpret_cast<const bf16x8*>(&Asrc[(size_t)arow_g * D + k]);
        }
#pragma unroll
        for (int t = 0; t < 2; t++) {
            int col = colbase + t * 16 + rl;
            bf16x8 b = *reinterpret_cast<const bf16x8*>(&Bc[(size_t)col * 256 + kc * 32 + koff]);
            acc[t] = __builtin_amdgcn_mfma_f32_16x16x32_bf16(a, b, acc[t], 0, 0, 0);
        }
    }

    // ---- epilogue: bias + relu + store (+ score partials), rows 0-7 only ----
    int rbase = kg * 4;
    float dotp[4] = {0.0f, 0.0f, 0.0f, 0.0f};
    float nrmp[4] = {0.0f, 0.0f, 0.0f, 0.0f};
    if (kg < 2) {
#pragma unroll
        for (int t = 0; t < 2; t++) {
            int col = colbase + t * 16 + rl;
            float bv = bias[col];
            float av = SCORE ? aux[col] : 0.0f;
#pragma unroll
            for (int rr = 0; rr < 4; rr++) {
                float v = acc[t][rr] + bv;
                if (RELU) v = fmaxf(v, 0.0f);
                int grow = row0 + rbase + rr;
                if (outf) outf[(size_t)grow * D + col] = v;
                else outb[(size_t)grow * D + col] = rne_bf16(v);
                dotp[rr] += v * av;
                nrmp[rr] += v * v;
            }
        }
    }

    if (SCORE) {
#pragma unroll
        for (int m = 1; m < 16; m <<= 1) {
#pragma unroll
            for (int rr = 0; rr < 4; rr++) {
                dotp[rr] += __shfl_xor(dotp[rr], m);
                nrmp[rr] += __shfl_xor(nrmp[rr], m);
            }
        }
        if (rl == 0 && kg < 2) {
#pragma unroll
            for (int rr = 0; rr < 4; rr++) {
                sdot[rbase + rr][wid] = dotp[rr];
                snrm[rbase + rr][wid] = nrmp[rr];
            }
        }
        __syncthreads();
        if (tid < 8) {
            float dot = sdot[tid][0] + sdot[tid][1] + sdot[tid][2] + sdot[tid][3];
            float nh  = snrm[tid][0] + snrm[tid][1] + snrm[tid][2] + snrm[tid][3];
            float hn = fmaxf(sqrtf(nh), 1e-8f);
            float sc = dot / (hn * an_s);
            sbuf[row0 + tid] = sc;
            wbuf[row0 + tid] = expf(-sc * sc);
        }
    }
}

// ---------- moments: 512 threads, 8 waves x 8 rows, LDS cross-wave reduce ----------
__global__ __launch_bounds__(512) void moments_kernel(const float* __restrict__ h,
                                                      const float* __restrict__ sbuf,
                                                      const float* __restrict__ wbuf,
                                                      float* __restrict__ M,
                                                      float* __restrict__ mden, int N) {
    __shared__ float lds[8 * KTERMS * D];     // 64 KB
    __shared__ float ldsm[8 * KTERMS];
    int tid = threadIdx.x;
    int w = tid >> 6, lane = tid & 63;
    int j0 = blockIdx.x * 64 + w * 8;

    float2 acc[KTERMS];
    float macc[KTERMS];
#pragma unroll
    for (int k = 0; k < KTERMS; k++) { acc[k] = make_float2(0.0f, 0.0f); macc[k] = 0.0f; }

    for (int j = j0; j < j0 + 8; j++) {
        float sj = sbuf[j];
        float wj = wbuf[j];
        float2 hv = *reinterpret_cast<const float2*>(&h[(size_t)j * D + lane * 2]);
        float coef = wj;
#pragma unroll
        for (int k = 0; k < KTERMS; k++) {
            acc[k].x += coef * hv.x;
            acc[k].y += coef * hv.y;
            macc[k] += coef;
            coef *= sj;
        }
    }

#pragma unroll
    for (int k = 0; k < KTERMS; k++) {
        lds[(w * KTERMS + k) * D + lane * 2]     = acc[k].x;
        lds[(w * KTERMS + k) * D + lane * 2 + 1] = acc[k].y;
    }
    if (lane == 0) {
#pragma unroll
        for (int k = 0; k < KTERMS; k++) ldsm[w * KTERMS + k] = macc[k];
    }
    __syncthreads();

    for (int e = tid; e < KTERMS * D; e += 512) {
        float s = 0.0f;
#pragma unroll
        for (int ww = 0; ww < 8; ww++) s += lds[ww * KTERMS * D + e];
        atomicAdd(&M[e], s);
    }
    if (tid < KTERMS) {
        float s = 0.0f;
#pragma unroll
        for (int ww = 0; ww < 8; ww++) s += ldsm[ww * KTERMS + tid];
        atomicAdd(&mden[tid], s);
    }
}

// ---------- fused z + classifier: out[n][c] = [h,z]@Wc^T + bc ----------
__global__ __launch_bounds__(128) void zcls_kernel(const float* __restrict__ M,
                                                   const float* __restrict__ mden,
                                                   const float* __restrict__ sbuf,
                                                   const float* __restrict__ h,
                                                   const float* __restrict__ Wc,
                                                   const float* __restrict__ bc,
                                                   float* __restrict__ out, int N) {
    const float A[KTERMS] = {1.0f, 2.0f, 2.0f, 1.3333334f, 0.6666667f, 0.26666668f,
                             0.08888889f, 0.025396826f, 0.0063492064f, 0.0014109347f,
                             2.8218695e-4f, 5.1306718e-5f, 8.5511196e-6f, 1.3155569e-6f,
                             1.8793670e-7f, 2.5058226e-8f};
    __shared__ float Ml[KTERMS * D];
    __shared__ float ml[KTERMS];
    __shared__ float wls[10 * 256];
    __shared__ float red[10][2];
    int tid = threadIdx.x;
    int lane = tid & 63, w = tid >> 6;
#pragma unroll
    for (int k = 0; k < KTERMS; k++) Ml[k * D + tid] = M[k * D + tid];
    if (tid < KTERMS) ml[tid] = mden[tid];
    for (int e = tid; e < 10 * 256; e += 128) wls[e] = Wc[e];
    __syncthreads();

    int n0 = blockIdx.x * 16;
    for (int n = n0; n < n0 + 16; n++) {
        float si = sbuf[n];
        float num = 0.0f, den = 0.0f, p = 1.0f;
#pragma unroll
        for (int k = 0; k < KTERMS; k++) {
            float ck = A[k] * p;
            num += ck * Ml[k * D + tid];
            den += ck * ml[k];
            p *= si;
        }
        float zc = num / den;
        float hc = h[(size_t)n * D + tid];

        float part[10];
#pragma unroll
        for (int c = 0; c < 10; c++)
            part[c] = hc * wls[c * 256 + tid] + zc * wls[c * 256 + 128 + tid];
#pragma unroll
        for (int m = 1; m < 64; m <<= 1) {
#pragma unroll
            for (int c = 0; c < 10; c++) part[c] += __shfl_xor(part[c], m);
        }
        if (lane == 0) {
#pragma unroll
            for (int c = 0; c < 10; c++) red[c][w] = part[c];
        }
        __syncthreads();
        if (tid < 10) out[(size_t)n * 10 + tid] = red[tid][0] + red[tid][1] + bc[tid];
        __syncthreads();
    }
}

extern "C" void kernel_launch(void* const* d_in, const int* in_sizes, int n_in,
                              void* d_out, int out_size, void* d_ws, size_t ws_size,
                              hipStream_t stream) {
    const float* x   = (const float*)d_in[0];
    const int*   ei  = (const int*)d_in[1];
    const float* W1l = (const float*)d_in[2];
    const float* b1l = (const float*)d_in[3];
    const float* W1r = (const float*)d_in[4];
    const float* W2l = (const float*)d_in[5];
    const float* b2l = (const float*)d_in[6];
    const float* W2r = (const float*)d_in[7];
    const float* aux = (const float*)d_in[8];
    const float* Wc  = (const float*)d_in[9];
    const float* bc  = (const float*)d_in[10];
    float* out = (float*)d_out;

    const int N = in_sizes[0] / D;
    const int E = in_sizes[1] / 2;
    const int* srcArr = ei;
    const int* dstArr = ei + E;
    const size_t ND = (size_t)N * D;

    // ---- workspace carve-up ----
    int* ip = (int*)d_ws;
    int* degi    = ip; ip += N;
    int* cursor  = ip; ip += N;
    int* rowptr  = ip; ip += N + 1;
    int* csr_src = ip; ip += E;
    uintptr_t up = ((uintptr_t)ip + 15) & ~(uintptr_t)15;
    short* sp = (short*)up;
    short* xb   = sp; sp += ND;
    short* h1b  = sp; sp += ND;
    short* Bc1  = sp; sp += 128 * 256;
    short* Bc2  = sp; sp += 128 * 256;
    up = ((uintptr_t)sp + 15) & ~(uintptr_t)15;
    float* p = (float*)up;
    float* invdeg = p; p += N;
    float* sbuf   = p; p += N;
    float* wbuf   = p; p += N;
    float* M      = p; p += KTERMS * D;
    float* mden   = p; p += KTERMS;
    float* h2     = p; p += ND;

    // prep: x->bf16, weight concat, zero degi/cursor and M/mden
    prep_kernel<<<1313, 256, 0, stream>>>(x, xb, W1l, W1r, W2l, W2r, Bc1, Bc2, degi, M);

    // build CSR (sorted by dst)
    degi_kernel<<<(E + 255) / 256, 256, 0, stream>>>(dstArr, degi, E);
    scan_kernel<<<1, 1024, 0, stream>>>(degi, rowptr, invdeg, N);
    fill_kernel<<<(E + 255) / 256, 256, 0, stream>>>(srcArr, dstArr, rowptr, cursor, csr_src, E);

    // layer 1: h1b = relu([gather(xb)|xb] @ Bc1^T + b1l)
    sage_fused_kernel<1, 0><<<N / 8, 256, 0, stream>>>(xb, Bc1, b1l, rowptr, csr_src, invdeg,
                                                       aux, h1b, nullptr, nullptr, nullptr);
    // layer 2: h2 = [gather(h1b)|h1b] @ Bc2^T + b2l, + score epilogue
    sage_fused_kernel<0, 1><<<N / 8, 256, 0, stream>>>(h1b, Bc2, b2l, rowptr, csr_src, invdeg,
                                                       aux, nullptr, h2, sbuf, wbuf);

    // Taylor moments
    moments_kernel<<<N / 64, 512, 0, stream>>>(h2, sbuf, wbuf, M, mden, N);

    // fused z + classifier
    zcls_kernel<<<N / 16, 128, 0, stream>>>(M, mden, sbuf, h2, Wc, bc, out, N);
}

// Round 16
// 131.466 us; speedup vs baseline: 2.1662x; 1.1798x over previous
//
#include <hip/hip_runtime.h>
#include <hip/hip_bf16.h>

#define D 128
#define KTERMS 16
#define ECAP 768

typedef __attribute__((ext_vector_type(8))) short bf16x8;
typedef __attribute__((ext_vector_type(4))) float f32x4;

__device__ inline short rne_bf16(float f) {
    union { float f; unsigned u; } v; v.f = f;
    unsigned r = (v.u + 0x7fffu + ((v.u >> 16) & 1u)) >> 16;
    return (short)r;
}
__device__ inline float bf16_to_f(unsigned s) {
    union { unsigned u; float f; } v; v.u = s << 16;
    return v.f;
}
__device__ inline unsigned pk2(float a, float b) {
    return (unsigned)(unsigned short)rne_bf16(a) | ((unsigned)(unsigned short)rne_bf16(b) << 16);
}
__device__ inline void addv(float* acc, uint4 v) {
    acc[0] += bf16_to_f(v.x & 0xffffu);
    acc[1] += bf16_to_f(v.x >> 16);
    acc[2] += bf16_to_f(v.y & 0xffffu);
    acc[3] += bf16_to_f(v.y >> 16);
    acc[4] += bf16_to_f(v.z & 0xffffu);
    acc[5] += bf16_to_f(v.z >> 16);
    acc[6] += bf16_to_f(v.w & 0xffffu);
    acc[7] += bf16_to_f(v.w >> 16);
}

// ---------- prep: cvt x->bf16 [0,1024) | weights [1024,1280) | zero ints [1280,1312) | zero M [1312] ----------
__global__ __launch_bounds__(256) void prep_kernel(const float* __restrict__ x,
                                                   short* __restrict__ xb,
                                                   const float* __restrict__ W1l,
                                                   const float* __restrict__ W1r,
                                                   const float* __restrict__ W2l,
                                                   const float* __restrict__ W2r,
                                                   short* __restrict__ Bc1,
                                                   short* __restrict__ Bc2,
                                                   int* __restrict__ zero_ints,   // degi+cursor, 2N ints
                                                   float* __restrict__ zero_f) {  // M+mden
    int b = blockIdx.x;
    int tid = threadIdx.x;
    if (b < 1024) {
        int base = (b * 256 + tid) * 8;
        const float4 a = *reinterpret_cast<const float4*>(&x[base]);
        const float4 c = *reinterpret_cast<const float4*>(&x[base + 4]);
        uint4 o;
        o.x = pk2(a.x, a.y);
        o.y = pk2(a.z, a.w);
        o.z = pk2(c.x, c.y);
        o.w = pk2(c.z, c.w);
        *reinterpret_cast<uint4*>(&xb[base]) = o;
    } else if (b < 1280) {
        int idx = (b - 1024) * 256 + tid;   // 65536 total
        int layer = idx >> 15;
        int rem = idx & 32767;
        int c = rem >> 8, k = rem & 255;
        const float* Wl = layer ? W2l : W1l;
        const float* Wr = layer ? W2r : W1r;
        float v = (k < 128) ? Wl[c * 128 + k] : Wr[c * 128 + (k - 128)];
        short* Bc = layer ? Bc2 : Bc1;
        Bc[c * 256 + k] = rne_bf16(v);
    } else if (b < 1312) {
        int idx = (b - 1280) * 256 + tid;   // 8192 int4 = 2N ints
        reinterpret_cast<int4*>(zero_ints)[idx] = make_int4(0, 0, 0, 0);
    } else {
        for (int e = tid; e < KTERMS * D + KTERMS; e += 256) zero_f[e] = 0.0f;
    }
}

// ---------- int degree histogram ----------
__global__ __launch_bounds__(256) void degi_kernel(const int* __restrict__ dst,
                                                   int* __restrict__ degi, int E) {
    int e = blockIdx.x * 256 + threadIdx.x;
    if (e < E) atomicAdd(&degi[dst[e]], 1);
}

// ---------- exclusive prefix scan of degi -> rowptr, plus invdeg ----------
__global__ __launch_bounds__(1024) void scan_kernel(const int* __restrict__ degi,
                                                    int* __restrict__ rowptr,
                                                    float* __restrict__ invdeg, int N) {
    __shared__ int part[1024];
    int tid = threadIdx.x;
    int base = tid * 16;
    int loc[16];
    int s = 0;
#pragma unroll
    for (int i = 0; i < 16; i++) {
        int d = degi[base + i];
        loc[i] = s; s += d;
        invdeg[base + i] = 1.0f / fmaxf((float)d, 1.0f);
    }
    part[tid] = s;
    __syncthreads();
    for (int off = 1; off < 1024; off <<= 1) {
        int t = (tid >= off) ? part[tid - off] : 0;
        __syncthreads();
        if (tid >= off) part[tid] += t;
        __syncthreads();
    }
    int prefix = part[tid] - s;  // exclusive
#pragma unroll
    for (int i = 0; i < 16; i++) rowptr[base + i] = prefix + loc[i];
    if (tid == 1023) rowptr[N] = prefix + s;
}

// ---------- CSR fill ----------
__global__ __launch_bounds__(256) void fill_kernel(const int* __restrict__ src,
                                                   const int* __restrict__ dst,
                                                   const int* __restrict__ rowptr,
                                                   int* __restrict__ cursor,
                                                   int* __restrict__ csr_src, int E) {
    int e = blockIdx.x * 256 + threadIdx.x;
    if (e < E) {
        int d = dst[e];
        int pos = atomicAdd(&cursor[d], 1);
        csr_src[rowptr[d] + pos] = src[e];
    }
}

// ---------- fused gather + MFMA SAGE (+ score epilogue when SCORE) ----------
// Block: 256 thr = 4 waves; 16 rows x 128 cols. Grid N/16 = 1024.
// Templated on <RELU,SCORE> so the two layers get distinct kernel names in rocprof.
template <int RELU, int SCORE>
__global__ __launch_bounds__(256) void sage_fused_kernel(const short* __restrict__ Asrc,
                                                         const short* __restrict__ Bc,
                                                         const float* __restrict__ bias,
                                                         const int* __restrict__ rowptr,
                                                         const int* __restrict__ csr_src,
                                                         const float* __restrict__ invdeg,
                                                         const float* __restrict__ aux,
                                                         short* __restrict__ outb,
                                                         float* __restrict__ outf,
                                                         float* __restrict__ sbuf,
                                                         float* __restrict__ wbuf) {
    __shared__ short aggl[16 * 128];      // 4 KB swizzled
    __shared__ int eidx[ECAP];            // 3 KB staged CSR indices
    __shared__ float sdot[16][4];
    __shared__ float snrm[16][4];
    __shared__ float an_s;

    int tid = threadIdx.x;
    int lane = tid & 63;
    int wid = tid >> 6;
    int row0 = blockIdx.x * 16;
    int sub = lane >> 4, sl = lane & 15;

    // stage this block's CSR index window into LDS (coalesced)
    int eb = rowptr[row0];
    int ecnt = rowptr[row0 + 16] - eb;
    for (int e = tid; e < ecnt && e < ECAP; e += 256) eidx[e] = csr_src[eb + e];

    if (SCORE && wid == 0) {
        float2 av = *reinterpret_cast<const float2*>(&aux[lane * 2]);
        float na = av.x * av.x + av.y * av.y;
        for (int m = 1; m < 64; m <<= 1) na += __shfl_xor(na, m);
        if (lane == 0) an_s = fmaxf(sqrtf(na), 1e-8f);
    }
    __syncthreads();

    // ---- gather phase: 1 node per 16-lane subgroup, LDS indices, unroll-4 ----
    int r = wid * 4 + sub;
    int node = row0 + r;
    int beg = rowptr[node], end = rowptr[node + 1];
    float inv = invdeg[node];
    float acc8[8] = {0.0f, 0.0f, 0.0f, 0.0f, 0.0f, 0.0f, 0.0f, 0.0f};
    int j = beg;
    for (; j + 3 < end; j += 4) {
        int jj = j - eb;
        int s0, s1, s2, s3;
        if (jj + 3 < ECAP) {
            s0 = eidx[jj]; s1 = eidx[jj + 1]; s2 = eidx[jj + 2]; s3 = eidx[jj + 3];
        } else {
            s0 = csr_src[j]; s1 = csr_src[j + 1]; s2 = csr_src[j + 2]; s3 = csr_src[j + 3];
        }
        uint4 v0 = *reinterpret_cast<const uint4*>(&Asrc[(size_t)s0 * D + sl * 8]);
        uint4 v1 = *reinterpret_cast<const uint4*>(&Asrc[(size_t)s1 * D + sl * 8]);
        uint4 v2 = *reinterpret_cast<const uint4*>(&Asrc[(size_t)s2 * D + sl * 8]);
        uint4 v3 = *reinterpret_cast<const uint4*>(&Asrc[(size_t)s3 * D + sl * 8]);
        addv(acc8, v0); addv(acc8, v1); addv(acc8, v2); addv(acc8, v3);
    }
    for (; j < end; j++) {
        int jj = j - eb;
        int s = (jj < ECAP) ? eidx[jj] : csr_src[j];
        uint4 v = *reinterpret_cast<const uint4*>(&Asrc[(size_t)s * D + sl * 8]);
        addv(acc8, v);
    }
    uint4 o;
    o.x = pk2(acc8[0] * inv, acc8[1] * inv);
    o.y = pk2(acc8[2] * inv, acc8[3] * inv);
    o.z = pk2(acc8[4] * inv, acc8[5] * inv);
    o.w = pk2(acc8[6] * inv, acc8[7] * inv);
    int wbyte = (r * 256 + sl * 16) ^ ((r & 7) << 4);
    *reinterpret_cast<uint4*>(reinterpret_cast<char*>(aggl) + wbyte) = o;
    __syncthreads();

    // ---- MFMA phase: wave owns 32 cols x 16 rows ----
    int colbase = wid * 32;
    int rl = lane & 15;
    int kg = lane >> 4;          // 0..3
    int koff = kg * 8;
    int arow_g = row0 + rl;

    f32x4 acc[2];
    acc[0] = (f32x4){0.0f, 0.0f, 0.0f, 0.0f};
    acc[1] = (f32x4){0.0f, 0.0f, 0.0f, 0.0f};

#pragma unroll
    for (int kc = 0; kc < 8; kc++) {
        bf16x8 a;
        if (kc < 4) {
            int rbyte = (rl * 256 + kc * 64 + kg * 16) ^ ((rl & 7) << 4);
            a = *reinterpret_cast<const bf16x8*>(reinterpret_cast<const char*>(aggl) + rbyte);
        } else {
            int k = (kc - 4) * 32 + koff;
            a = *reinterpret_cast<const bf16x8*>(&Asrc[(size_t)arow_g * D + k]);
        }
#pragma unroll
        for (int t = 0; t < 2; t++) {
            int col = colbase + t * 16 + rl;
            bf16x8 b = *reinterpret_cast<const bf16x8*>(&Bc[(size_t)col * 256 + kc * 32 + koff]);
            acc[t] = __builtin_amdgcn_mfma_f32_16x16x32_bf16(a, b, acc[t], 0, 0, 0);
        }
    }

    // ---- epilogue: bias + relu + store (+ score partials) ----
    int rbase = kg * 4;
    float dotp[4] = {0.0f, 0.0f, 0.0f, 0.0f};
    float nrmp[4] = {0.0f, 0.0f, 0.0f, 0.0f};
#pragma unroll
    for (int t = 0; t < 2; t++) {
        int col = colbase + t * 16 + rl;
        float bv = bias[col];
        float av = SCORE ? aux[col] : 0.0f;
#pragma unroll
        for (int rr = 0; rr < 4; rr++) {
            float v = acc[t][rr] + bv;
            if (RELU) v = fmaxf(v, 0.0f);
            int grow = row0 + rbase + rr;
            if (outf) outf[(size_t)grow * D + col] = v;
            else outb[(size_t)grow * D + col] = rne_bf16(v);
            dotp[rr] += v * av;
            nrmp[rr] += v * v;
        }
    }

    if (SCORE) {
#pragma unroll
        for (int m = 1; m < 16; m <<= 1) {
#pragma unroll
            for (int rr = 0; rr < 4; rr++) {
                dotp[rr] += __shfl_xor(dotp[rr], m);
                nrmp[rr] += __shfl_xor(nrmp[rr], m);
            }
        }
        if (rl == 0) {
#pragma unroll
            for (int rr = 0; rr < 4; rr++) {
                sdot[rbase + rr][wid] = dotp[rr];
                snrm[rbase + rr][wid] = nrmp[rr];
            }
        }
        __syncthreads();
        if (tid < 16) {
            float dot = sdot[tid][0] + sdot[tid][1] + sdot[tid][2] + sdot[tid][3];
            float nh  = snrm[tid][0] + snrm[tid][1] + snrm[tid][2] + snrm[tid][3];
            float hn = fmaxf(sqrtf(nh), 1e-8f);
            float sc = dot / (hn * an_s);
            sbuf[row0 + tid] = sc;
            wbuf[row0 + tid] = expf(-sc * sc);
        }
    }
}

// ---------- moments: 512 threads, 8 waves x 8 rows, LDS cross-wave reduce ----------
__global__ __launch_bounds__(512) void moments_kernel(const float* __restrict__ h,
                                                      const float* __restrict__ sbuf,
                                                      const float* __restrict__ wbuf,
                                                      float* __restrict__ M,
                                                      float* __restrict__ mden, int N) {
    __shared__ float lds[8 * KTERMS * D];     // 64 KB
    __shared__ float ldsm[8 * KTERMS];
    int tid = threadIdx.x;
    int w = tid >> 6, lane = tid & 63;
    int j0 = blockIdx.x * 64 + w * 8;

    float2 acc[KTERMS];
    float macc[KTERMS];
#pragma unroll
    for (int k = 0; k < KTERMS; k++) { acc[k] = make_float2(0.0f, 0.0f); macc[k] = 0.0f; }

    for (int j = j0; j < j0 + 8; j++) {
        float sj = sbuf[j];
        float wj = wbuf[j];
        float2 hv = *reinterpret_cast<const float2*>(&h[(size_t)j * D + lane * 2]);
        float coef = wj;
#pragma unroll
        for (int k = 0; k < KTERMS; k++) {
            acc[k].x += coef * hv.x;
            acc[k].y += coef * hv.y;
            macc[k] += coef;
            coef *= sj;
        }
    }

#pragma unroll
    for (int k = 0; k < KTERMS; k++) {
        lds[(w * KTERMS + k) * D + lane * 2]     = acc[k].x;
        lds[(w * KTERMS + k) * D + lane * 2 + 1] = acc[k].y;
    }
    if (lane == 0) {
#pragma unroll
        for (int k = 0; k < KTERMS; k++) ldsm[w * KTERMS + k] = macc[k];
    }
    __syncthreads();

    for (int e = tid; e < KTERMS * D; e += 512) {
        float s = 0.0f;
#pragma unroll
        for (int ww = 0; ww < 8; ww++) s += lds[ww * KTERMS * D + e];
        atomicAdd(&M[e], s);
    }
    if (tid < KTERMS) {
        float s = 0.0f;
#pragma unroll
        for (int ww = 0; ww < 8; ww++) s += ldsm[ww * KTERMS + tid];
        atomicAdd(&mden[tid], s);
    }
}

// ---------- fused z + classifier: out[n][c] = [h,z]@Wc^T + bc ----------
__global__ __launch_bounds__(128) void zcls_kernel(const float* __restrict__ M,
                                                   const float* __restrict__ mden,
                                                   const float* __restrict__ sbuf,
                                                   const float* __restrict__ h,
                                                   const float* __restrict__ Wc,
                                                   const float* __restrict__ bc,
                                                   float* __restrict__ out, int N) {
    const float A[KTERMS] = {1.0f, 2.0f, 2.0f, 1.3333334f, 0.6666667f, 0.26666668f,
                             0.08888889f, 0.025396826f, 0.0063492064f, 0.0014109347f,
                             2.8218695e-4f, 5.1306718e-5f, 8.5511196e-6f, 1.3155569e-6f,
                             1.8793670e-7f, 2.5058226e-8f};
    __shared__ float Ml[KTERMS * D];
    __shared__ float ml[KTERMS];
    __shared__ float wls[10 * 256];
    __shared__ float red[10][2];
    int tid = threadIdx.x;
    int lane = tid & 63, w = tid >> 6;
#pragma unroll
    for (int k = 0; k < KTERMS; k++) Ml[k * D + tid] = M[k * D + tid];
    if (tid < KTERMS) ml[tid] = mden[tid];
    for (int e = tid; e < 10 * 256; e += 128) wls[e] = Wc[e];
    __syncthreads();

    int n0 = blockIdx.x * 16;
    for (int n = n0; n < n0 + 16; n++) {
        float si = sbuf[n];
        float num = 0.0f, den = 0.0f, p = 1.0f;
#pragma unroll
        for (int k = 0; k < KTERMS; k++) {
            float ck = A[k] * p;
            num += ck * Ml[k * D + tid];
            den += ck * ml[k];
            p *= si;
        }
        float zc = num / den;
        float hc = h[(size_t)n * D + tid];

        float part[10];
#pragma unroll
        for (int c = 0; c < 10; c++)
            part[c] = hc * wls[c * 256 + tid] + zc * wls[c * 256 + 128 + tid];
#pragma unroll
        for (int m = 1; m < 64; m <<= 1) {
#pragma unroll
            for (int c = 0; c < 10; c++) part[c] += __shfl_xor(part[c], m);
        }
        if (lane == 0) {
#pragma unroll
            for (int c = 0; c < 10; c++) red[c][w] = part[c];
        }
        __syncthreads();
        if (tid < 10) out[(size_t)n * 10 + tid] = red[tid][0] + red[tid][1] + bc[tid];
        __syncthreads();
    }
}

extern "C" void kernel_launch(void* const* d_in, const int* in_sizes, int n_in,
                              void* d_out, int out_size, void* d_ws, size_t ws_size,
                              hipStream_t stream) {
    const float* x   = (const float*)d_in[0];
    const int*   ei  = (const int*)d_in[1];
    const float* W1l = (const float*)d_in[2];
    const float* b1l = (const float*)d_in[3];
    const float* W1r = (const float*)d_in[4];
    const float* W2l = (const float*)d_in[5];
    const float* b2l = (const float*)d_in[6];
    const float* W2r = (const float*)d_in[7];
    const float* aux = (const float*)d_in[8];
    const float* Wc  = (const float*)d_in[9];
    const float* bc  = (const float*)d_in[10];
    float* out = (float*)d_out;

    const int N = in_sizes[0] / D;
    const int E = in_sizes[1] / 2;
    const int* srcArr = ei;
    const int* dstArr = ei + E;
    const size_t ND = (size_t)N * D;

    // ---- workspace carve-up ----
    int* ip = (int*)d_ws;
    int* degi    = ip; ip += N;
    int* cursor  = ip; ip += N;
    int* rowptr  = ip; ip += N + 1;
    int* csr_src = ip; ip += E;
    uintptr_t up = ((uintptr_t)ip + 15) & ~(uintptr_t)15;
    short* sp = (short*)up;
    short* xb   = sp; sp += ND;
    short* h1b  = sp; sp += ND;
    short* Bc1  = sp; sp += 128 * 256;
    short* Bc2  = sp; sp += 128 * 256;
    up = ((uintptr_t)sp + 15) & ~(uintptr_t)15;
    float* p = (float*)up;
    float* invdeg = p; p += N;
    float* sbuf   = p; p += N;
    float* wbuf   = p; p += N;
    float* M      = p; p += KTERMS * D;
    float* mden   = p; p += KTERMS;
    float* h2     = p; p += ND;

    // prep: x->bf16, weight concat, zero degi/cursor and M/mden
    prep_kernel<<<1313, 256, 0, stream>>>(x, xb, W1l, W1r, W2l, W2r, Bc1, Bc2, degi, M);

    // build CSR (sorted by dst)
    degi_kernel<<<(E + 255) / 256, 256, 0, stream>>>(dstArr, degi, E);
    scan_kernel<<<1, 1024, 0, stream>>>(degi, rowptr, invdeg, N);
    fill_kernel<<<(E + 255) / 256, 256, 0, stream>>>(srcArr, dstArr, rowptr, cursor, csr_src, E);

    // layer 1: h1b = relu([gather(xb)|xb] @ Bc1^T + b1l)
    sage_fused_kernel<1, 0><<<N / 16, 256, 0, stream>>>(xb, Bc1, b1l, rowptr, csr_src, invdeg,
                                                        aux, h1b, nullptr, nullptr, nullptr);
    // layer 2: h2 = [gather(h1b)|h1b] @ Bc2^T + b2l, + score epilogue
    sage_fused_kernel<0, 1><<<N / 16, 256, 0, stream>>>(h1b, Bc2, b2l, rowptr, csr_src, invdeg,
                                                        aux, nullptr, h2, sbuf, wbuf);

    // Taylor moments
    moments_kernel<<<N / 64, 512, 0, stream>>>(h2, sbuf, wbuf, M, mden, N);

    // fused z + classifier
    zcls_kernel<<<N / 16, 128, 0, stream>>>(M, mden, sbuf, h2, Wc, bc, out, N);
}